// Round 8
// baseline (1127.753 us; speedup 1.0000x reference)
//
#include <hip/hip_runtime.h>
#include <hip/hip_cooperative_groups.h>
#include <cstdint>
#include <cstddef>

namespace cg = cooperative_groups;

// SS2D: B=2, H=W=64 (L=4096), D_MODEL=96, D_INNER=192, K=4 dirs, N=16 states, DT_RANK=6.
// R10-R15: see journal. R16 FAILED: 768-block cooperative launch rejected (output zeros).
// R17: cooperative retry, hedged. 512 blocks x launch_bounds(256,2) (co-residency trivially
//      valid: 2 blocks/CU, VGPR cap 256, 48KB LDS/CU), __threadfence before each grid.sync,
//      and host-side FALLBACK to the verbatim R15 9-kernel path if the cooperative launch
//      returns any error (incl. during graph capture).

#define CHUNK 16
#define NCK   256   // 4096 / CHUNK
#define SPAN  32    // chunks per span
#define NSP   8     // NCK / SPAN

#if __has_builtin(__builtin_amdgcn_exp2f)
#define EXP2(x) __builtin_amdgcn_exp2f(x)
#else
#define EXP2(x) exp2f(x)
#endif
#define LOG2E 1.44269504088896340736f
#define LN2   0.69314718055994530942f

typedef __attribute__((ext_vector_type(8))) short short8;
typedef __attribute__((ext_vector_type(8))) unsigned short ushort8;
typedef __attribute__((ext_vector_type(4))) float f32x4;

__device__ __forceinline__ float siluf(float x){ return x * (1.f/(1.f+__expf(-x))); }
__device__ __forceinline__ float softplus_fast(float v){
  float e  = EXP2(v*LOG2E);
  float sp = LN2*__log2f(1.f + e);
  return (v > 20.f) ? v : sp;
}
__device__ __forceinline__ unsigned short f2b(float f){
  uint32_t u = __float_as_uint(f);
  uint32_t r = (u + 0x7fffu + ((u>>16)&1u)) >> 16;
  return (unsigned short)r;
}
__device__ __forceinline__ short8 cast8(const float* p){
  float4 f0 = *(const float4*)p;
  float4 f1 = *(const float4*)(p+4);
  unsigned short t[8] = {f2b(f0.x),f2b(f0.y),f2b(f0.z),f2b(f0.w),
                         f2b(f1.x),f2b(f1.y),f2b(f1.z),f2b(f1.w)};
  return *(short8*)t;
}

struct Pm {
  const float *x,*Win,*bin,*cw,*cb,*Wxp,*bxp,*Wdt,*bdt,*Alog,*Dskip,*dtb,*Wout,*bout,*gamma,*beta;
  float *xx,*zs,*xc,*xdbl,*ysb,*Sb,*H0loc,*sdtb,*dts_c,*ylcs,*cloc,*SpanS,*SpanC,*H0span;
  unsigned short *xcb,*xcTb,*Wf,*Wfin,*Wfout;
  float *out;
};

// ======================= device phase bodies (shared by both paths) =======================

__device__ __forceinline__ void ph_pack(const Pm& p, int gtid){
  int lane = gtid & 63;
  int n = lane & 15, q = lane >> 4;
  if (gtid < 18432){
    int rest = gtid >> 6;
    int pt = rest % 6; rest /= 6;
    int k32 = rest & 3; rest >>= 2;
    int kc = rest % 6; int ph = rest / 6;
    int pp = ph*96 + pt*16 + n;
    int kbase = kc*128 + k32*32 + q*8;
    unsigned short v[8];
#pragma unroll
    for (int j = 0; j < 8; j++)
      v[j] = (pp < 152) ? f2b(p.Wxp[(size_t)pp*768 + kbase + j]) : (unsigned short)0;
    *(ushort8*)(p.Wf + (size_t)gtid*8) = *(ushort8*)v;
  } else if (gtid < 23040){
    int e = gtid - 18432;
    int rest = e >> 6;
    int nt = rest % 24, k32 = rest / 24;
    int pp = nt*16 + n;
    int kbase = k32*32 + q*8;
    unsigned short v[8];
#pragma unroll
    for (int j = 0; j < 8; j++) v[j] = f2b(p.Win[(size_t)pp*96 + kbase + j]);
    *(ushort8*)(p.Wfin + (size_t)e*8) = *(ushort8*)v;
  } else if (gtid < 25344){
    int e = gtid - 23040;
    int rest = e >> 6;
    int nt = rest % 6, k32 = rest / 6;
    int pp = nt*16 + n;
    int kbase = k32*32 + q*8;
    unsigned short v[8];
#pragma unroll
    for (int j = 0; j < 8; j++) v[j] = f2b(p.Wout[(size_t)pp*192 + kbase + j]);
    *(ushort8*)(p.Wfout + (size_t)e*8) = *(ushort8*)v;
  }
}

__device__ __forceinline__ void ph_gemm_in(const Pm& p, int vb, int tid){
  const int lane = tid & 63, w = tid >> 6;
  const int m0 = vb*32;
  const int n = lane & 15, q = lane >> 4;
  f32x4 acc[2][6] = {};
#pragma unroll
  for (int k32 = 0; k32 < 3; k32++){
    int kb = k32*32 + q*8;
    short8 a[2];
#pragma unroll
    for (int mf = 0; mf < 2; mf++)
      a[mf] = cast8(p.x + (size_t)(m0 + mf*16 + n)*96 + kb);
#pragma unroll
    for (int j = 0; j < 6; j++){
      int nt = w*6 + j;
      short8 bfr = *(const short8*)(p.Wfin + ((size_t)(k32*24 + nt)*64 + lane)*8);
#pragma unroll
      for (int mf = 0; mf < 2; mf++)
        acc[mf][j] = __builtin_amdgcn_mfma_f32_16x16x32_bf16(a[mf], bfr, acc[mf][j], 0, 0, 0);
    }
  }
#pragma unroll
  for (int mf = 0; mf < 2; mf++)
#pragma unroll
    for (int j = 0; j < 6; j++){
      int nn = w*96 + j*16 + n;
      float bv = p.bin[nn];
#pragma unroll
      for (int reg = 0; reg < 4; reg++){
        int l = m0 + mf*16 + q*4 + reg;
        float v = acc[mf][j][reg] + bv;
        if (nn < 192) p.xx[(size_t)l*192 + nn] = v;
        else          p.zs[(size_t)l*192 + (nn-192)] = siluf(v);
      }
    }
}

__device__ __forceinline__ void ph_conv(const Pm& p, int gid){
  int c4 = gid % 48; int c = c4*4;
  int l = (gid/48) & 4095;
  int b = gid / (48*4096);
  int h = l >> 6, w2 = l & 63;
  float sx = 0.f, sy = 0.f, sz = 0.f, sw = 0.f;
#pragma unroll
  for (int kh = 0; kh < 3; kh++){
    int h2 = h + kh - 1;
    if ((unsigned)h2 >= 64u) continue;
#pragma unroll
    for (int kw = 0; kw < 3; kw++){
      int w3 = w2 + kw - 1;
      if ((unsigned)w3 >= 64u) continue;
      float4 v = *(const float4*)(p.xx + ((size_t)b*4096 + h2*64 + w3)*192 + c);
      int o = kh*3 + kw;
      sx = fmaf(v.x, p.cw[(c+0)*9 + o], sx);
      sy = fmaf(v.y, p.cw[(c+1)*9 + o], sy);
      sz = fmaf(v.z, p.cw[(c+2)*9 + o], sz);
      sw = fmaf(v.w, p.cw[(c+3)*9 + o], sw);
    }
  }
  float4 cbv = *(const float4*)(p.cb + c);
  float4 s;
  s.x = siluf(sx + cbv.x); s.y = siluf(sy + cbv.y);
  s.z = siluf(sz + cbv.z); s.w = siluf(sw + cbv.w);
  unsigned short sb[4] = {f2b(s.x), f2b(s.y), f2b(s.z), f2b(s.w)};
  size_t i0 = ((size_t)b*4096 + l)*192 + c;
  *(float4*)(p.xc + i0) = s;
  *(uint2*)(p.xcb + i0) = *(uint2*)sb;
  int tl = (l & 63)*64 + (l >> 6);
  *(uint2*)(p.xcTb + ((size_t)b*4096 + tl)*192 + c) = *(uint2*)sb;
}

__device__ __forceinline__ void ph_xdbl(const Pm& p, int vb, int tid, unsigned short* SH){
  const int lane = tid & 63, w = tid >> 6;
  const int wl = w & 1, wp = w >> 1;
  const int l0 = (vb & 63)*64, ph = (vb >> 6) & 1, b = vb >> 7;
  const int n = lane & 15, q = lane >> 4;
  f32x4 acc[2][3] = {};
  const unsigned short* slab0 = p.Wf + (size_t)ph*6*12288;
  for (int kc = 0; kc < 6; kc++){
    __syncthreads();
    const ushort8* srcp = (const ushort8*)(slab0 + (size_t)kc*12288);
#pragma unroll
    for (int t = 0; t < 6; t++) ((ushort8*)SH)[tid + t*256] = srcp[tid + t*256];
    __syncthreads();
#pragma unroll
    for (int k32 = 0; k32 < 4; k32++){
      int kk = kc*128 + k32*32;
      int dir = kk/192; int ch = kk%192 + q*8;
      const unsigned short* sp = (dir & 1) ? p.xcTb : p.xcb;
      bool rev = (dir >= 2);
      short8 a[2];
#pragma unroll
      for (int mt = 0; mt < 2; mt++){
        int ls = l0 + wl*32 + mt*16 + n;
        int row = rev ? 4095 - ls : ls;
        a[mt] = *(const short8*)(sp + ((size_t)b*4096 + row)*192 + ch);
      }
#pragma unroll
      for (int j = 0; j < 3; j++){
        short8 bfr = *(const short8*)&SH[((size_t)(k32*6 + wp*3 + j)*64 + lane)*8];
#pragma unroll
        for (int mt = 0; mt < 2; mt++)
          acc[mt][j] = __builtin_amdgcn_mfma_f32_16x16x32_bf16(a[mt], bfr, acc[mt][j], 0, 0, 0);
      }
    }
  }
#pragma unroll
  for (int mt = 0; mt < 2; mt++)
#pragma unroll
    for (int j = 0; j < 3; j++){
      int pp = ph*96 + (wp*3+j)*16 + n;
      if (pp < 152){
        int k = pp/38, ppp = pp%38;
        int off = (ppp < 6) ? ppp : ppp + 2;
        float bias = p.bxp[pp];
#pragma unroll
        for (int reg = 0; reg < 4; reg++){
          int l = l0 + wl*32 + mt*16 + q*4 + reg;
          float val = acc[mt][j][reg] + bias;
          p.xdbl[(((size_t)b*4 + k)*4096 + l)*48 + off] = val;
          if (ppp < 6) p.dts_c[((size_t)b*4096 + l)*24 + k*6 + ppp] = val;
        }
      }
    }
}

__device__ __forceinline__ void ph_scanA(const Pm& p, int vb, int tid){
  const int lane = tid & 63;
  const int wid  = __builtin_amdgcn_readfirstlane(vb*4 + (tid >> 6));
  const int ck = wid & (NCK-1); const int g = wid / NCK;
  const int dblk = g % 3; const int bk = g / 3;
  const int k = bk & 3; const int b = bk >> 2;
  const int d = dblk*64 + lane; const int ch = k*192 + d;
  float An[16];
  {
    const float4* ap = (const float4*)(p.Alog + (size_t)ch*16);
#pragma unroll
    for (int i = 0; i < 4; i++){
      float4 t = ap[i];
      An[4*i+0] = -LOG2E*__expf(t.x); An[4*i+1] = -LOG2E*__expf(t.y);
      An[4*i+2] = -LOG2E*__expf(t.z); An[4*i+3] = -LOG2E*__expf(t.w);
    }
  }
  float Wr[24];
#pragma unroll
  for (int r = 0; r < 24; r++) Wr[r] = p.Wdt[(size_t)ch*24 + r];
  const float bsum = p.bdt[ch] + p.dtb[ch];
  const float Dv = p.Dskip[ch];
  const int l0 = ck*CHUNK;
  const bool rev = (k >= 2);
  const int tr = k & 1;
  const int T0 = tr ? ((l0 & 63)*64 + (l0 >> 6)) : l0;
  const int rs = tr ? 64 : 1;
  const int row0 = rev ? 4095 - T0 : T0;
  const int rstep = (rev ? -rs : rs)*192;
  const float* up  = p.xc + ((size_t)b*4096 + row0)*192 + d;
  const float* qc  = p.dts_c + ((size_t)b*4096 + l0)*24;
  const float* xbc = p.xdbl + (((size_t)b*4 + k)*4096 + l0)*48;
  float* ylp = p.ylcs + ((((size_t)b*4 + k)*2048 + (size_t)ck*(CHUNK/2))*192 + d)*4;
  float h[16];
#pragma unroll
  for (int n = 0; n < 16; n++) h[n] = 0.f;
  float sdt = 0.f;
#pragma unroll 4
  for (int tp = 0; tp < CHUNK/2; tp++){
    float y2[2], cs2[2];
#pragma unroll
    for (int e = 0; e < 2; e++){
      float u  = up[0];
      float4 B0 = *(const float4*)(xbc + 8);
      float4 B1 = *(const float4*)(xbc + 12);
      float4 B2 = *(const float4*)(xbc + 16);
      float4 B3 = *(const float4*)(xbc + 20);
      float4 C0 = *(const float4*)(xbc + 24);
      float4 C1 = *(const float4*)(xbc + 28);
      float4 C2 = *(const float4*)(xbc + 32);
      float4 C3 = *(const float4*)(xbc + 36);
      float Bv[16] = {B0.x,B0.y,B0.z,B0.w, B1.x,B1.y,B1.z,B1.w,
                      B2.x,B2.y,B2.z,B2.w, B3.x,B3.y,B3.z,B3.w};
      float Cv[16] = {C0.x,C0.y,C0.z,C0.w, C1.x,C1.y,C1.z,C1.w,
                      C2.x,C2.y,C2.z,C2.w, C3.x,C3.y,C3.z,C3.w};
      float4 q0 = *(const float4*)(qc);
      float4 q1 = *(const float4*)(qc + 4);
      float4 q2 = *(const float4*)(qc + 8);
      float4 q3 = *(const float4*)(qc + 12);
      float4 q4 = *(const float4*)(qc + 16);
      float4 q5 = *(const float4*)(qc + 20);
      float qv[24] = {q0.x,q0.y,q0.z,q0.w, q1.x,q1.y,q1.z,q1.w,
                      q2.x,q2.y,q2.z,q2.w, q3.x,q3.y,q3.z,q3.w,
                      q4.x,q4.y,q4.z,q4.w, q5.x,q5.y,q5.z,q5.w};
      float v0 = bsum, v1 = 0.f, v2 = 0.f, v3 = 0.f;
#pragma unroll
      for (int r = 0; r < 24; r += 4){
        v0 = fmaf(Wr[r+0], qv[r+0], v0);
        v1 = fmaf(Wr[r+1], qv[r+1], v1);
        v2 = fmaf(Wr[r+2], qv[r+2], v2);
        v3 = fmaf(Wr[r+3], qv[r+3], v3);
      }
      float dt = softplus_fast((v0+v1) + (v2+v3));
      float dtu = dt*u;
      sdt += dt;
      float y0 = u*Dv;
      float y1 = 0.f;
#pragma unroll
      for (int n = 0; n < 16; n += 2){
        float dA0 = EXP2(dt*An[n]);
        float dA1 = EXP2(dt*An[n+1]);
        h[n]   = fmaf(dA0, h[n],   dtu*Bv[n]);
        h[n+1] = fmaf(dA1, h[n+1], dtu*Bv[n+1]);
        y0 = fmaf(h[n],   Cv[n],   y0);
        y1 = fmaf(h[n+1], Cv[n+1], y1);
      }
      y2[e] = y0 + y1; cs2[e] = sdt;
      qc += 24; xbc += 48; up += rstep;
    }
    *(float4*)ylp = make_float4(y2[0], cs2[0], y2[1], cs2[1]);
    ylp += 768;
  }
  size_t rb = ((size_t)wid*64 + lane);
  p.sdtb[rb] = sdt;
  *(float4*)(p.Sb + rb*16 + 0)  = make_float4(h[0], h[1], h[2], h[3]);
  *(float4*)(p.Sb + rb*16 + 4)  = make_float4(h[4], h[5], h[6], h[7]);
  *(float4*)(p.Sb + rb*16 + 8)  = make_float4(h[8], h[9], h[10],h[11]);
  *(float4*)(p.Sb + rb*16 + 12) = make_float4(h[12],h[13],h[14],h[15]);
}

__device__ __forceinline__ void ph_scanB1(const Pm& p, int gtid){
  int n = gtid & 15; int lane = (gtid >> 4) & 63;
  int span = (gtid >> 10) & (NSP-1); int g = gtid >> 13;
  int dblk = g % 3; int bk = g / 3; int k = bk & 3;
  int ch = k*192 + dblk*64 + lane;
  float An = -LOG2E*__expf(p.Alog[(size_t)ch*16 + n]);
  float h = 0.f, cs = 0.f;
  int wid0 = g*NCK + span*SPAN;
#pragma unroll 8
  for (int c = 0; c < SPAN; c++){
    size_t rb = ((size_t)(wid0 + c)*64 + lane);
    p.H0loc[rb*16 + n] = h;
    if (n == 0) p.cloc[rb] = cs;
    float sd = p.sdtb[rb];
    h = fmaf(EXP2(An*sd), h, p.Sb[rb*16 + n]);
    cs += sd;
  }
  size_t sp = ((size_t)(g*NSP + span)*64 + lane);
  p.SpanS[sp*16 + n] = h;
  if (n == 0) p.SpanC[sp] = cs;
}

__device__ __forceinline__ void ph_scanB2(const Pm& p, int gtid){
  int n = gtid & 15; int lane = (gtid >> 4) & 63; int g = gtid >> 10;
  int dblk = g % 3; int bk = g / 3; int k = bk & 3;
  int ch = k*192 + dblk*64 + lane;
  float An = -LOG2E*__expf(p.Alog[(size_t)ch*16 + n]);
  float h = 0.f;
#pragma unroll
  for (int span = 0; span < NSP; span++){
    size_t sp = ((size_t)(g*NSP + span)*64 + lane);
    p.H0span[sp*16 + n] = h;
    h = fmaf(EXP2(An*p.SpanC[sp]), h, p.SpanS[sp*16 + n]);
  }
}

__device__ __forceinline__ void ph_scanC(const Pm& p, int vb, int tid){
  const int lane = tid & 63;
  const int wid  = __builtin_amdgcn_readfirstlane(vb*4 + (tid >> 6));
  const int ck = wid & (NCK-1); const int g = wid / NCK;
  const int dblk = g % 3; const int bk = g / 3;
  const int k = bk & 3; const int b = bk >> 2;
  const int d = dblk*64 + lane; const int ch = k*192 + d;
  float An[16];
  {
    const float4* ap = (const float4*)(p.Alog + (size_t)ch*16);
#pragma unroll
    for (int i = 0; i < 4; i++){
      float4 t = ap[i];
      An[4*i+0] = -LOG2E*__expf(t.x); An[4*i+1] = -LOG2E*__expf(t.y);
      An[4*i+2] = -LOG2E*__expf(t.z); An[4*i+3] = -LOG2E*__expf(t.w);
    }
  }
  const int l0 = ck*CHUNK;
  const bool rev = (k >= 2);
  const int tr = k & 1;
  const int T0 = tr ? ((l0 & 63)*64 + (l0 >> 6)) : l0;
  const int rs = tr ? 64 : 1;
  const int row0 = rev ? 4095 - T0 : T0;
  const int rstep = (rev ? -rs : rs)*192;
  const float* xbc = p.xdbl + (((size_t)b*4 + k)*4096 + l0)*48;
  const float* ylp = p.ylcs + ((((size_t)b*4 + k)*2048 + (size_t)ck*(CHUNK/2))*192 + d)*4;
  float* ysp = p.ysb + ((size_t)(k*2 + b))*4096*192 + (size_t)row0*192 + d;
  float h0r[16];
  {
    size_t rb = ((size_t)wid*64 + lane);
    float cl = p.cloc[rb];
    size_t sp = ((size_t)(g*NSP + (ck >> 5))*64 + lane);
#pragma unroll
    for (int i = 0; i < 4; i++){
      float4 hl = *(const float4*)(p.H0loc + rb*16 + i*4);
      float4 hs = *(const float4*)(p.H0span + sp*16 + i*4);
      h0r[4*i+0] = fmaf(EXP2(An[4*i+0]*cl), hs.x, hl.x);
      h0r[4*i+1] = fmaf(EXP2(An[4*i+1]*cl), hs.y, hl.y);
      h0r[4*i+2] = fmaf(EXP2(An[4*i+2]*cl), hs.z, hl.z);
      h0r[4*i+3] = fmaf(EXP2(An[4*i+3]*cl), hs.w, hl.w);
    }
  }
#pragma unroll 4
  for (int tp = 0; tp < CHUNK/2; tp++){
    float4 yc = *(const float4*)ylp;
#pragma unroll
    for (int e = 0; e < 2; e++){
      float yl = e ? yc.z : yc.x;
      float cs = e ? yc.w : yc.y;
      float4 C0 = *(const float4*)(xbc + 24);
      float4 C1 = *(const float4*)(xbc + 28);
      float4 C2 = *(const float4*)(xbc + 32);
      float4 C3 = *(const float4*)(xbc + 36);
      float Cv[16] = {C0.x,C0.y,C0.z,C0.w, C1.x,C1.y,C1.z,C1.w,
                      C2.x,C2.y,C2.z,C2.w, C3.x,C3.y,C3.z,C3.w};
      float y0 = yl, y1 = 0.f;
#pragma unroll
      for (int n = 0; n < 16; n += 2){
        float e0 = EXP2(An[n]*cs)   * h0r[n];
        float e1 = EXP2(An[n+1]*cs) * h0r[n+1];
        y0 = fmaf(Cv[n],   e0, y0);
        y1 = fmaf(Cv[n+1], e1, y1);
      }
      ysp[0] = y0 + y1;
      xbc += 48; ysp += rstep;
    }
    ylp += 768;
  }
}

__device__ __forceinline__ void ph_lngemm(const Pm& p, int vb, int tid, unsigned short* SH){
  {
    const int row_l = tid >> 3, o = tid & 7;
    const int row = vb*32 + row_l;
    const int b = row >> 12, l = row & 4095;
    const int c0 = o*24;
    float s[24];
#pragma unroll
    for (int j = 0; j < 6; j++){
      float sx = 0.f, sy = 0.f, sz = 0.f, sw = 0.f;
#pragma unroll
      for (int k = 0; k < 4; k++){
        float4 t = *(const float4*)(p.ysb + (((size_t)(k*2+b))*4096 + l)*192 + c0 + j*4);
        sx += t.x; sy += t.y; sz += t.z; sw += t.w;
      }
      s[j*4+0]=sx; s[j*4+1]=sy; s[j*4+2]=sz; s[j*4+3]=sw;
    }
    float tot = 0.f;
#pragma unroll
    for (int j = 0; j < 24; j++) tot += s[j];
#pragma unroll
    for (int off = 1; off < 8; off <<= 1) tot += __shfl_xor(tot, off);
    float mean = tot*(1.f/192.f);
    float vs = 0.f;
#pragma unroll
    for (int j = 0; j < 24; j++){ s[j] -= mean; vs = fmaf(s[j], s[j], vs); }
#pragma unroll
    for (int off = 1; off < 8; off <<= 1) vs += __shfl_xor(vs, off);
    float rstd = rsqrtf(vs*(1.f/192.f) + 1e-5f);
    unsigned short vb2[24];
#pragma unroll
    for (int j = 0; j < 6; j++){
      float4 g4 = *(const float4*)(p.gamma + c0 + j*4);
      float4 b4 = *(const float4*)(p.beta  + c0 + j*4);
      float4 z4 = *(const float4*)(p.zs + (size_t)row*192 + c0 + j*4);
      vb2[j*4+0] = f2b((s[j*4+0]*rstd*g4.x + b4.x)*z4.x);
      vb2[j*4+1] = f2b((s[j*4+1]*rstd*g4.y + b4.y)*z4.y);
      vb2[j*4+2] = f2b((s[j*4+2]*rstd*g4.z + b4.z)*z4.z);
      vb2[j*4+3] = f2b((s[j*4+3]*rstd*g4.w + b4.w)*z4.w);
    }
#pragma unroll
    for (int j = 0; j < 3; j++)
      *(ushort8*)(SH + row_l*200 + c0 + j*8) = *(ushort8*)(vb2 + j*8);
  }
  __syncthreads();
  const int lane = tid & 63, w = tid >> 6;
  const int wm = w & 1, wn = w >> 1;
  const int n = lane & 15, q = lane >> 4;
  const int m0 = vb*32 + wm*16;
  f32x4 acc[3] = {};
#pragma unroll
  for (int k32 = 0; k32 < 6; k32++){
    int kb = k32*32 + q*8;
    short8 a = *(const short8*)(SH + (wm*16 + n)*200 + kb);
#pragma unroll
    for (int j = 0; j < 3; j++){
      int nt = wn*3 + j;
      short8 bfr = *(const short8*)(p.Wfout + ((size_t)(k32*6 + nt)*64 + lane)*8);
      acc[j] = __builtin_amdgcn_mfma_f32_16x16x32_bf16(a, bfr, acc[j], 0, 0, 0);
    }
  }
#pragma unroll
  for (int j = 0; j < 3; j++){
    int nn = wn*48 + j*16 + n;
    float bv = p.bout[nn];
#pragma unroll
    for (int reg = 0; reg < 4; reg++){
      int m = m0 + q*4 + reg;
      p.out[(size_t)m*96 + nn] = acc[j][reg] + bv;
    }
  }
}

// ======================= cooperative mega-kernel (512 blocks, 2/CU) =======================
__global__ __launch_bounds__(256, 2) void k_all(Pm p)
{
  cg::grid_group grid = cg::this_grid();
  __shared__ unsigned short SH[12288];   // 24 KB
  const int bid = blockIdx.x;            // 0..511
  const int tid = threadIdx.x;

  ph_pack(p, bid*256 + tid);
  __threadfence(); grid.sync();

  if (bid < 256) ph_gemm_in(p, bid, tid);
  __threadfence(); grid.sync();

  for (int vb = bid; vb < 1536; vb += 512) ph_conv(p, vb*256 + tid);
  __threadfence(); grid.sync();

  if (bid < 256) ph_xdbl(p, bid, tid, SH);
  __threadfence(); grid.sync();

  for (int vb = bid; vb < 1536; vb += 512) ph_scanA(p, vb, tid);
  __threadfence(); grid.sync();

  for (int vb = bid; vb < 768; vb += 512) ph_scanB1(p, vb*256 + tid);
  __threadfence(); grid.sync();

  if (bid < 96) ph_scanB2(p, bid*256 + tid);
  __threadfence(); grid.sync();

  for (int vb = bid; vb < 1536; vb += 512) ph_scanC(p, vb, tid);
  __threadfence(); grid.sync();

  if (bid < 256) ph_lngemm(p, bid, tid, SH);
}

// ======================= fallback individual kernels (R15 path) =======================
__global__ __launch_bounds__(256) void k_pack_f(Pm p){ ph_pack(p, blockIdx.x*256 + threadIdx.x); }
__global__ __launch_bounds__(256) void k_gemm_in_f(Pm p){ ph_gemm_in(p, blockIdx.x, threadIdx.x); }
__global__ __launch_bounds__(256) void k_conv_f(Pm p){ ph_conv(p, blockIdx.x*256 + threadIdx.x); }
__global__ __launch_bounds__(256) void k_xdbl_f(Pm p){
  __shared__ unsigned short SH[12288];
  ph_xdbl(p, blockIdx.x, threadIdx.x, SH);
}
__global__ __launch_bounds__(256) void k_scanA_f(Pm p){ ph_scanA(p, blockIdx.x, threadIdx.x); }
__global__ __launch_bounds__(256) void k_scanB1_f(Pm p){ ph_scanB1(p, blockIdx.x*256 + threadIdx.x); }
__global__ __launch_bounds__(256) void k_scanB2_f(Pm p){ ph_scanB2(p, blockIdx.x*256 + threadIdx.x); }
__global__ __launch_bounds__(256) void k_scanC_f(Pm p){ ph_scanC(p, blockIdx.x, threadIdx.x); }
__global__ __launch_bounds__(256) void k_lngemm_f(Pm p){
  __shared__ unsigned short SH[12288];
  ph_lngemm(p, blockIdx.x, threadIdx.x, SH);
}

extern "C" void kernel_launch(void* const* d_in, const int* in_sizes, int n_in,
                              void* d_out, int out_size, void* d_ws, size_t ws_size,
                              hipStream_t stream)
{
  float* ws = (float*)d_ws;
  Pm p;
  p.x      = (const float*)d_in[0];
  p.Win    = (const float*)d_in[1];
  p.bin    = (const float*)d_in[2];
  p.cw     = (const float*)d_in[3];
  p.cb     = (const float*)d_in[4];
  p.Wxp    = (const float*)d_in[5];
  p.bxp    = (const float*)d_in[6];
  p.Wdt    = (const float*)d_in[7];
  p.bdt    = (const float*)d_in[8];
  p.Alog   = (const float*)d_in[9];
  p.Dskip  = (const float*)d_in[10];
  p.dtb    = (const float*)d_in[11];
  p.Wout   = (const float*)d_in[12];
  p.bout   = (const float*)d_in[13];
  p.gamma  = (const float*)d_in[14];
  p.beta   = (const float*)d_in[15];
  p.out    = (float*)d_out;

  p.xx     = ws;                 // 1572864
  p.zs     = ws + 1572864;       // 1572864
  p.xc     = ws + 3145728;       // 1572864
  p.xdbl   = ws + 4718592;       // 1572864
  p.ysb    = ws + 6291456;       // 6291456
  p.Sb     = ws + 12582912;      // 6291456  [wid][lane][16]
  p.H0loc  = ws + 18874368;      // 6291456  [wid][lane][16]
  p.sdtb   = ws + 25165824;      // 393216
  p.dts_c  = ws + 25559040;      // 196608
  p.ylcs   = ws + 25755648;      // 12582912 paired {y0,cs0,y1,cs1}
  p.cloc   = ws + 38338560;      // 393216
  p.SpanS  = ws + 38731776;      // 196608
  p.SpanC  = ws + 38928384;      // 12288
  p.H0span = ws + 38940672;      // 196608
  p.xcb    = (unsigned short*)(ws + 39137280); // 1572864 ushort
  p.xcTb   = p.xcb + 1572864;                  // 1572864 ushort
  p.Wf     = (unsigned short*)(ws + 40710144); // 147456 ushort
  p.Wfin   = (unsigned short*)(ws + 40783872); // 36864 ushort
  p.Wfout  = (unsigned short*)(ws + 40802304); // 18432 ushort

  void* args[] = { &p };
  hipError_t err = hipLaunchCooperativeKernel((const void*)k_all, dim3(512), dim3(256),
                                              args, 0, stream);
  if (err != hipSuccess){
    (void)hipGetLastError();   // clear sticky error so graph capture isn't poisoned
    k_pack_f   <<<99,   256, 0, stream>>>(p);
    k_gemm_in_f<<<256,  256, 0, stream>>>(p);
    k_conv_f   <<<1536, 256, 0, stream>>>(p);
    k_xdbl_f   <<<256,  256, 0, stream>>>(p);
    k_scanA_f  <<<1536, 256, 0, stream>>>(p);
    k_scanB1_f <<<768,  256, 0, stream>>>(p);
    k_scanB2_f <<<96,   256, 0, stream>>>(p);
    k_scanC_f  <<<1536, 256, 0, stream>>>(p);
    k_lngemm_f <<<256,  256, 0, stream>>>(p);
  }
}

// Round 9
// 238.995 us; speedup vs baseline: 4.7187x; 4.7187x over previous
//
#include <hip/hip_runtime.h>
#include <cstdint>
#include <cstddef>

// SS2D: B=2, H=W=64 (L=4096), D_MODEL=96, D_INNER=192, K=4 dirs, N=16 states, DT_RANK=6.
// R10-R15: see journal; plateau 207-210us. R16/R17: cooperative mega-kernel FALSIFIED —
//   grid.sync() ~115us each on MI355X (8 non-coherent XCD L2s); 1127us total. Counters
//   gained: total pipeline HBM traffic ~280MB (44us BW floor), LDS conflicts ~0.
// R18: restore 9-kernel R15 path (bit-exact) + k_xdbl Wf staging double-buffered
//   (48KB LDS, stage kc+1 under MFMA of kc, 6 barriers instead of 12 — xdbl runs at
//   1 block/CU so every barrier was fully exposed).

#define CHUNK 16
#define NCK   256   // 4096 / CHUNK
#define SPAN  32    // chunks per span
#define NSP   8     // NCK / SPAN

#if __has_builtin(__builtin_amdgcn_exp2f)
#define EXP2(x) __builtin_amdgcn_exp2f(x)
#else
#define EXP2(x) exp2f(x)
#endif
#define LOG2E 1.44269504088896340736f
#define LN2   0.69314718055994530942f

typedef __attribute__((ext_vector_type(8))) short short8;
typedef __attribute__((ext_vector_type(8))) unsigned short ushort8;
typedef __attribute__((ext_vector_type(4))) float f32x4;

__device__ __forceinline__ float siluf(float x){ return x * (1.f/(1.f+__expf(-x))); }
__device__ __forceinline__ float softplus_fast(float v){
  float e  = EXP2(v*LOG2E);
  float sp = LN2*__log2f(1.f + e);
  return (v > 20.f) ? v : sp;
}
__device__ __forceinline__ unsigned short f2b(float f){
  uint32_t u = __float_as_uint(f);
  uint32_t r = (u + 0x7fffu + ((u>>16)&1u)) >> 16;
  return (unsigned short)r;
}
__device__ __forceinline__ short8 cast8(const float* p){
  float4 f0 = *(const float4*)p;
  float4 f1 = *(const float4*)(p+4);
  unsigned short t[8] = {f2b(f0.x),f2b(f0.y),f2b(f0.z),f2b(f0.w),
                         f2b(f1.x),f2b(f1.y),f2b(f1.z),f2b(f1.w)};
  return *(short8*)t;
}

struct Pm {
  const float *x,*Win,*bin,*cw,*cb,*Wxp,*bxp,*Wdt,*bdt,*Alog,*Dskip,*dtb,*Wout,*bout,*gamma,*beta;
  float *xx,*zs,*xc,*xdbl,*ysb,*Sb,*H0loc,*sdtb,*dts_c,*ylcs,*cloc,*SpanS,*SpanC,*H0span;
  unsigned short *xcb,*xcTb,*Wf,*Wfin,*Wfout;
  float *out;
};

// ---------------- Stage 0: pack ----------------
__global__ __launch_bounds__(256) void k_pack(Pm p)
{
  int gtid = blockIdx.x*256 + threadIdx.x;   // 25344 lane-entries
  int lane = gtid & 63;
  int n = lane & 15, q = lane >> 4;
  if (gtid < 18432){
    int rest = gtid >> 6;
    int pt = rest % 6; rest /= 6;
    int k32 = rest & 3; rest >>= 2;
    int kc = rest % 6; int ph = rest / 6;
    int pp = ph*96 + pt*16 + n;
    int kbase = kc*128 + k32*32 + q*8;
    unsigned short v[8];
#pragma unroll
    for (int j = 0; j < 8; j++)
      v[j] = (pp < 152) ? f2b(p.Wxp[(size_t)pp*768 + kbase + j]) : (unsigned short)0;
    *(ushort8*)(p.Wf + (size_t)gtid*8) = *(ushort8*)v;
  } else if (gtid < 23040){
    int e = gtid - 18432;
    int rest = e >> 6;
    int nt = rest % 24, k32 = rest / 24;
    int pp = nt*16 + n;
    int kbase = k32*32 + q*8;
    unsigned short v[8];
#pragma unroll
    for (int j = 0; j < 8; j++) v[j] = f2b(p.Win[(size_t)pp*96 + kbase + j]);
    *(ushort8*)(p.Wfin + (size_t)e*8) = *(ushort8*)v;
  } else if (gtid < 25344){
    int e = gtid - 23040;
    int rest = e >> 6;
    int nt = rest % 6, k32 = rest / 6;
    int pp = nt*16 + n;
    int kbase = k32*32 + q*8;
    unsigned short v[8];
#pragma unroll
    for (int j = 0; j < 8; j++) v[j] = f2b(p.Wout[(size_t)pp*192 + kbase + j]);
    *(ushort8*)(p.Wfout + (size_t)e*8) = *(ushort8*)v;
  }
}

// ---------------- Stage 1 (MFMA): gemm_in, 32-row blocks, grid 256 ----------------
__global__ __launch_bounds__(256) void k_gemm_in(Pm p)
{
  const int tid = threadIdx.x;
  const int lane = tid & 63, w = tid >> 6;
  const int m0 = blockIdx.x*32;
  const int n = lane & 15, q = lane >> 4;
  f32x4 acc[2][6] = {};
#pragma unroll
  for (int k32 = 0; k32 < 3; k32++){
    int kb = k32*32 + q*8;
    short8 a[2];
#pragma unroll
    for (int mf = 0; mf < 2; mf++)
      a[mf] = cast8(p.x + (size_t)(m0 + mf*16 + n)*96 + kb);
#pragma unroll
    for (int j = 0; j < 6; j++){
      int nt = w*6 + j;
      short8 bfr = *(const short8*)(p.Wfin + ((size_t)(k32*24 + nt)*64 + lane)*8);
#pragma unroll
      for (int mf = 0; mf < 2; mf++)
        acc[mf][j] = __builtin_amdgcn_mfma_f32_16x16x32_bf16(a[mf], bfr, acc[mf][j], 0, 0, 0);
    }
  }
#pragma unroll
  for (int mf = 0; mf < 2; mf++)
#pragma unroll
    for (int j = 0; j < 6; j++){
      int nn = w*96 + j*16 + n;
      float bv = p.bin[nn];
#pragma unroll
      for (int reg = 0; reg < 4; reg++){
        int l = m0 + mf*16 + q*4 + reg;
        float v = acc[mf][j][reg] + bv;
        if (nn < 192) p.xx[(size_t)l*192 + nn] = v;
        else          p.zs[(size_t)l*192 + (nn-192)] = siluf(v);
      }
    }
}

// ---------------- Stage 2: conv, 4ch/thread float4 ----------------
__global__ __launch_bounds__(256) void k_conv(Pm p)
{
  int gid = blockIdx.x*256 + threadIdx.x;   // 393216
  int c4 = gid % 48; int c = c4*4;
  int l = (gid/48) & 4095;
  int b = gid / (48*4096);
  int h = l >> 6, w2 = l & 63;
  float sx = 0.f, sy = 0.f, sz = 0.f, sw = 0.f;
#pragma unroll
  for (int kh = 0; kh < 3; kh++){
    int h2 = h + kh - 1;
    if ((unsigned)h2 >= 64u) continue;
#pragma unroll
    for (int kw = 0; kw < 3; kw++){
      int w3 = w2 + kw - 1;
      if ((unsigned)w3 >= 64u) continue;
      float4 v = *(const float4*)(p.xx + ((size_t)b*4096 + h2*64 + w3)*192 + c);
      int o = kh*3 + kw;
      sx = fmaf(v.x, p.cw[(c+0)*9 + o], sx);
      sy = fmaf(v.y, p.cw[(c+1)*9 + o], sy);
      sz = fmaf(v.z, p.cw[(c+2)*9 + o], sz);
      sw = fmaf(v.w, p.cw[(c+3)*9 + o], sw);
    }
  }
  float4 cbv = *(const float4*)(p.cb + c);
  float4 s;
  s.x = siluf(sx + cbv.x); s.y = siluf(sy + cbv.y);
  s.z = siluf(sz + cbv.z); s.w = siluf(sw + cbv.w);
  unsigned short sb[4] = {f2b(s.x), f2b(s.y), f2b(s.z), f2b(s.w)};
  size_t i0 = ((size_t)b*4096 + l)*192 + c;
  *(float4*)(p.xc + i0) = s;
  *(uint2*)(p.xcb + i0) = *(uint2*)sb;
  int tl = (l & 63)*64 + (l >> 6);
  *(uint2*)(p.xcTb + ((size_t)b*4096 + tl)*192 + c) = *(uint2*)sb;
}

// ---------------- Stage 3 (MFMA): xdbl, R18 double-buffered Wf staging ----------------
// grid (64,2,2) = 256 blocks (1/CU). LDS 48KB: stage kc+1 under MFMA(kc); 1 barrier/kc.
__global__ __launch_bounds__(256) void k_xdbl(Pm p)
{
  __shared__ unsigned short Bsh[2*12288];   // 48 KB
  const int tid = threadIdx.x;
  const int lane = tid & 63, w = tid >> 6;
  const int wl = w & 1, wp = w >> 1;
  const int l0 = blockIdx.x*64, ph = blockIdx.y, b = blockIdx.z;
  const int n = lane & 15, q = lane >> 4;
  f32x4 acc[2][3] = {};
  const unsigned short* slab0 = p.Wf + (size_t)ph*6*12288;
  {
    const ushort8* srcp = (const ushort8*)slab0;
#pragma unroll
    for (int t = 0; t < 6; t++) ((ushort8*)Bsh)[tid + t*256] = srcp[tid + t*256];
  }
  __syncthreads();
  int buf = 0;
  for (int kc = 0; kc < 6; kc++){
    if (kc < 5){
      const ushort8* srcp = (const ushort8*)(slab0 + (size_t)(kc+1)*12288);
      ushort8* dst = (ushort8*)(Bsh + (buf^1)*12288);
#pragma unroll
      for (int t = 0; t < 6; t++) dst[tid + t*256] = srcp[tid + t*256];
    }
    const unsigned short* Bcur = Bsh + buf*12288;
#pragma unroll
    for (int k32 = 0; k32 < 4; k32++){
      int kk = kc*128 + k32*32;
      int dir = kk/192; int ch = kk%192 + q*8;
      const unsigned short* sp = (dir & 1) ? p.xcTb : p.xcb;
      bool rev = (dir >= 2);
      short8 a[2];
#pragma unroll
      for (int mt = 0; mt < 2; mt++){
        int ls = l0 + wl*32 + mt*16 + n;
        int row = rev ? 4095 - ls : ls;
        a[mt] = *(const short8*)(sp + ((size_t)b*4096 + row)*192 + ch);
      }
#pragma unroll
      for (int j = 0; j < 3; j++){
        short8 bfr = *(const short8*)&Bcur[((size_t)(k32*6 + wp*3 + j)*64 + lane)*8];
#pragma unroll
        for (int mt = 0; mt < 2; mt++)
          acc[mt][j] = __builtin_amdgcn_mfma_f32_16x16x32_bf16(a[mt], bfr, acc[mt][j], 0, 0, 0);
      }
    }
    __syncthreads();
    buf ^= 1;
  }
#pragma unroll
  for (int mt = 0; mt < 2; mt++)
#pragma unroll
    for (int j = 0; j < 3; j++){
      int pp = ph*96 + (wp*3+j)*16 + n;
      if (pp < 152){
        int k = pp/38, ppp = pp%38;
        int off = (ppp < 6) ? ppp : ppp + 2;
        float bias = p.bxp[pp];
#pragma unroll
        for (int reg = 0; reg < 4; reg++){
          int l = l0 + wl*32 + mt*16 + q*4 + reg;
          float val = acc[mt][j][reg] + bias;
          p.xdbl[(((size_t)b*4 + k)*4096 + l)*48 + off] = val;
          if (ppp < 6) p.dts_c[((size_t)b*4096 + l)*24 + k*6 + ppp] = val;
        }
      }
    }
}

// ---------------- scanA: dt + local recurrence; paired {y,cs} float4 stream ----------------
__global__ __launch_bounds__(256) void k_scanA(Pm p)
{
  const int tid = threadIdx.x;
  const int lane = tid & 63;
  const int wid  = __builtin_amdgcn_readfirstlane(blockIdx.x*4 + (tid >> 6));
  const int ck = wid & (NCK-1); const int g = wid / NCK;
  const int dblk = g % 3; const int bk = g / 3;
  const int k = bk & 3; const int b = bk >> 2;
  const int d = dblk*64 + lane; const int ch = k*192 + d;
  float An[16];
  {
    const float4* ap = (const float4*)(p.Alog + (size_t)ch*16);
#pragma unroll
    for (int i = 0; i < 4; i++){
      float4 t = ap[i];
      An[4*i+0] = -LOG2E*__expf(t.x); An[4*i+1] = -LOG2E*__expf(t.y);
      An[4*i+2] = -LOG2E*__expf(t.z); An[4*i+3] = -LOG2E*__expf(t.w);
    }
  }
  float Wr[24];
#pragma unroll
  for (int r = 0; r < 24; r++) Wr[r] = p.Wdt[(size_t)ch*24 + r];
  const float bsum = p.bdt[ch] + p.dtb[ch];
  const float Dv = p.Dskip[ch];
  const int l0 = ck*CHUNK;
  const bool rev = (k >= 2);
  const int tr = k & 1;
  const int T0 = tr ? ((l0 & 63)*64 + (l0 >> 6)) : l0;
  const int rs = tr ? 64 : 1;
  const int row0 = rev ? 4095 - T0 : T0;
  const int rstep = (rev ? -rs : rs)*192;
  const float* up  = p.xc + ((size_t)b*4096 + row0)*192 + d;
  const float* qc  = p.dts_c + ((size_t)b*4096 + l0)*24;
  const float* xbc = p.xdbl + (((size_t)b*4 + k)*4096 + l0)*48;
  float* ylp = p.ylcs + ((((size_t)b*4 + k)*2048 + (size_t)ck*(CHUNK/2))*192 + d)*4;
  float h[16];
#pragma unroll
  for (int n = 0; n < 16; n++) h[n] = 0.f;
  float sdt = 0.f;
#pragma unroll 4
  for (int tp = 0; tp < CHUNK/2; tp++){
    float y2[2], cs2[2];
#pragma unroll
    for (int e = 0; e < 2; e++){
      float u  = up[0];
      float4 B0 = *(const float4*)(xbc + 8);
      float4 B1 = *(const float4*)(xbc + 12);
      float4 B2 = *(const float4*)(xbc + 16);
      float4 B3 = *(const float4*)(xbc + 20);
      float4 C0 = *(const float4*)(xbc + 24);
      float4 C1 = *(const float4*)(xbc + 28);
      float4 C2 = *(const float4*)(xbc + 32);
      float4 C3 = *(const float4*)(xbc + 36);
      float Bv[16] = {B0.x,B0.y,B0.z,B0.w, B1.x,B1.y,B1.z,B1.w,
                      B2.x,B2.y,B2.z,B2.w, B3.x,B3.y,B3.z,B3.w};
      float Cv[16] = {C0.x,C0.y,C0.z,C0.w, C1.x,C1.y,C1.z,C1.w,
                      C2.x,C2.y,C2.z,C2.w, C3.x,C3.y,C3.z,C3.w};
      float4 q0 = *(const float4*)(qc);
      float4 q1 = *(const float4*)(qc + 4);
      float4 q2 = *(const float4*)(qc + 8);
      float4 q3 = *(const float4*)(qc + 12);
      float4 q4 = *(const float4*)(qc + 16);
      float4 q5 = *(const float4*)(qc + 20);
      float qv[24] = {q0.x,q0.y,q0.z,q0.w, q1.x,q1.y,q1.z,q1.w,
                      q2.x,q2.y,q2.z,q2.w, q3.x,q3.y,q3.z,q3.w,
                      q4.x,q4.y,q4.z,q4.w, q5.x,q5.y,q5.z,q5.w};
      float v0 = bsum, v1 = 0.f, v2 = 0.f, v3 = 0.f;
#pragma unroll
      for (int r = 0; r < 24; r += 4){
        v0 = fmaf(Wr[r+0], qv[r+0], v0);
        v1 = fmaf(Wr[r+1], qv[r+1], v1);
        v2 = fmaf(Wr[r+2], qv[r+2], v2);
        v3 = fmaf(Wr[r+3], qv[r+3], v3);
      }
      float dt = softplus_fast((v0+v1) + (v2+v3));
      float dtu = dt*u;
      sdt += dt;
      float y0 = u*Dv;
      float y1 = 0.f;
#pragma unroll
      for (int n = 0; n < 16; n += 2){
        float dA0 = EXP2(dt*An[n]);
        float dA1 = EXP2(dt*An[n+1]);
        h[n]   = fmaf(dA0, h[n],   dtu*Bv[n]);
        h[n+1] = fmaf(dA1, h[n+1], dtu*Bv[n+1]);
        y0 = fmaf(h[n],   Cv[n],   y0);
        y1 = fmaf(h[n+1], Cv[n+1], y1);
      }
      y2[e] = y0 + y1; cs2[e] = sdt;
      qc += 24; xbc += 48; up += rstep;
    }
    *(float4*)ylp = make_float4(y2[0], cs2[0], y2[1], cs2[1]);
    ylp += 768;
  }
  size_t rb = ((size_t)wid*64 + lane);
  p.sdtb[rb] = sdt;
  *(float4*)(p.Sb + rb*16 + 0)  = make_float4(h[0], h[1], h[2], h[3]);
  *(float4*)(p.Sb + rb*16 + 4)  = make_float4(h[4], h[5], h[6], h[7]);
  *(float4*)(p.Sb + rb*16 + 8)  = make_float4(h[8], h[9], h[10],h[11]);
  *(float4*)(p.Sb + rb*16 + 12) = make_float4(h[12],h[13],h[14],h[15]);
}

// ---------------- scanB1: intra-span prefixes, n-fastest map ----------------
__global__ __launch_bounds__(256) void k_scanB1(Pm p)
{
  int gtid = blockIdx.x*256 + threadIdx.x;   // 196608
  int n = gtid & 15; int lane = (gtid >> 4) & 63;
  int span = (gtid >> 10) & (NSP-1); int g = gtid >> 13;
  int dblk = g % 3; int bk = g / 3; int k = bk & 3;
  int ch = k*192 + dblk*64 + lane;
  float An = -LOG2E*__expf(p.Alog[(size_t)ch*16 + n]);
  float h = 0.f, cs = 0.f;
  int wid0 = g*NCK + span*SPAN;
#pragma unroll 8
  for (int c = 0; c < SPAN; c++){
    size_t rb = ((size_t)(wid0 + c)*64 + lane);
    p.H0loc[rb*16 + n] = h;
    if (n == 0) p.cloc[rb] = cs;
    float sd = p.sdtb[rb];
    h = fmaf(EXP2(An*sd), h, p.Sb[rb*16 + n]);
    cs += sd;
  }
  size_t sp = ((size_t)(g*NSP + span)*64 + lane);
  p.SpanS[sp*16 + n] = h;
  if (n == 0) p.SpanC[sp] = cs;
}

// ---------------- scanB2: span chains ----------------
__global__ __launch_bounds__(256) void k_scanB2(Pm p)
{
  int gtid = blockIdx.x*256 + threadIdx.x;  // 24576
  int n = gtid & 15; int lane = (gtid >> 4) & 63; int g = gtid >> 10;
  int dblk = g % 3; int bk = g / 3; int k = bk & 3;
  int ch = k*192 + dblk*64 + lane;
  float An = -LOG2E*__expf(p.Alog[(size_t)ch*16 + n]);
  float h = 0.f;
#pragma unroll
  for (int span = 0; span < NSP; span++){
    size_t sp = ((size_t)(g*NSP + span)*64 + lane);
    p.H0span[sp*16 + n] = h;
    h = fmaf(EXP2(An*p.SpanC[sp]), h, p.SpanS[sp*16 + n]);
  }
}

// ---------------- scanC: recurrence-free ----------------
__global__ __launch_bounds__(256) void k_scanC(Pm p)
{
  const int tid = threadIdx.x;
  const int lane = tid & 63;
  const int wid  = __builtin_amdgcn_readfirstlane(blockIdx.x*4 + (tid >> 6));
  const int ck = wid & (NCK-1); const int g = wid / NCK;
  const int dblk = g % 3; const int bk = g / 3;
  const int k = bk & 3; const int b = bk >> 2;
  const int d = dblk*64 + lane; const int ch = k*192 + d;
  float An[16];
  {
    const float4* ap = (const float4*)(p.Alog + (size_t)ch*16);
#pragma unroll
    for (int i = 0; i < 4; i++){
      float4 t = ap[i];
      An[4*i+0] = -LOG2E*__expf(t.x); An[4*i+1] = -LOG2E*__expf(t.y);
      An[4*i+2] = -LOG2E*__expf(t.z); An[4*i+3] = -LOG2E*__expf(t.w);
    }
  }
  const int l0 = ck*CHUNK;
  const bool rev = (k >= 2);
  const int tr = k & 1;
  const int T0 = tr ? ((l0 & 63)*64 + (l0 >> 6)) : l0;
  const int rs = tr ? 64 : 1;
  const int row0 = rev ? 4095 - T0 : T0;
  const int rstep = (rev ? -rs : rs)*192;
  const float* xbc = p.xdbl + (((size_t)b*4 + k)*4096 + l0)*48;
  const float* ylp = p.ylcs + ((((size_t)b*4 + k)*2048 + (size_t)ck*(CHUNK/2))*192 + d)*4;
  float* ysp = p.ysb + ((size_t)(k*2 + b))*4096*192 + (size_t)row0*192 + d;
  float h0r[16];
  {
    size_t rb = ((size_t)wid*64 + lane);
    float cl = p.cloc[rb];
    size_t sp = ((size_t)(g*NSP + (ck >> 5))*64 + lane);
#pragma unroll
    for (int i = 0; i < 4; i++){
      float4 hl = *(const float4*)(p.H0loc + rb*16 + i*4);
      float4 hs = *(const float4*)(p.H0span + sp*16 + i*4);
      h0r[4*i+0] = fmaf(EXP2(An[4*i+0]*cl), hs.x, hl.x);
      h0r[4*i+1] = fmaf(EXP2(An[4*i+1]*cl), hs.y, hl.y);
      h0r[4*i+2] = fmaf(EXP2(An[4*i+2]*cl), hs.z, hl.z);
      h0r[4*i+3] = fmaf(EXP2(An[4*i+3]*cl), hs.w, hl.w);
    }
  }
#pragma unroll 4
  for (int tp = 0; tp < CHUNK/2; tp++){
    float4 yc = *(const float4*)ylp;
#pragma unroll
    for (int e = 0; e < 2; e++){
      float yl = e ? yc.z : yc.x;
      float cs = e ? yc.w : yc.y;
      float4 C0 = *(const float4*)(xbc + 24);
      float4 C1 = *(const float4*)(xbc + 28);
      float4 C2 = *(const float4*)(xbc + 32);
      float4 C3 = *(const float4*)(xbc + 36);
      float Cv[16] = {C0.x,C0.y,C0.z,C0.w, C1.x,C1.y,C1.z,C1.w,
                      C2.x,C2.y,C2.z,C2.w, C3.x,C3.y,C3.z,C3.w};
      float y0 = yl, y1 = 0.f;
#pragma unroll
      for (int n = 0; n < 16; n += 2){
        float e0 = EXP2(An[n]*cs)   * h0r[n];
        float e1 = EXP2(An[n+1]*cs) * h0r[n+1];
        y0 = fmaf(Cv[n],   e0, y0);
        y1 = fmaf(Cv[n+1], e1, y1);
      }
      ysp[0] = y0 + y1;
      xbc += 48; ysp += rstep;
    }
    ylp += 768;
  }
}

// ---------------- lngemm: merge + LN*silu(z) -> LDS bf16 -> MFMA out ----------------
__global__ __launch_bounds__(256) void k_lngemm(Pm p)
{
  __shared__ unsigned short Ash[32*200];   // 12.5 KB
  const int tid = threadIdx.x;
  {
    const int row_l = tid >> 3, o = tid & 7;
    const int row = blockIdx.x*32 + row_l;
    const int b = row >> 12, l = row & 4095;
    const int c0 = o*24;
    float s[24];
#pragma unroll
    for (int j = 0; j < 6; j++){
      float sx = 0.f, sy = 0.f, sz = 0.f, sw = 0.f;
#pragma unroll
      for (int k = 0; k < 4; k++){
        float4 t = *(const float4*)(p.ysb + (((size_t)(k*2+b))*4096 + l)*192 + c0 + j*4);
        sx += t.x; sy += t.y; sz += t.z; sw += t.w;
      }
      s[j*4+0]=sx; s[j*4+1]=sy; s[j*4+2]=sz; s[j*4+3]=sw;
    }
    float tot = 0.f;
#pragma unroll
    for (int j = 0; j < 24; j++) tot += s[j];
#pragma unroll
    for (int off = 1; off < 8; off <<= 1) tot += __shfl_xor(tot, off);
    float mean = tot*(1.f/192.f);
    float vs = 0.f;
#pragma unroll
    for (int j = 0; j < 24; j++){ s[j] -= mean; vs = fmaf(s[j], s[j], vs); }
#pragma unroll
    for (int off = 1; off < 8; off <<= 1) vs += __shfl_xor(vs, off);
    float rstd = rsqrtf(vs*(1.f/192.f) + 1e-5f);
    unsigned short vb2[24];
#pragma unroll
    for (int j = 0; j < 6; j++){
      float4 g4 = *(const float4*)(p.gamma + c0 + j*4);
      float4 b4 = *(const float4*)(p.beta  + c0 + j*4);
      float4 z4 = *(const float4*)(p.zs + (size_t)row*192 + c0 + j*4);
      vb2[j*4+0] = f2b((s[j*4+0]*rstd*g4.x + b4.x)*z4.x);
      vb2[j*4+1] = f2b((s[j*4+1]*rstd*g4.y + b4.y)*z4.y);
      vb2[j*4+2] = f2b((s[j*4+2]*rstd*g4.z + b4.z)*z4.z);
      vb2[j*4+3] = f2b((s[j*4+3]*rstd*g4.w + b4.w)*z4.w);
    }
#pragma unroll
    for (int j = 0; j < 3; j++)
      *(ushort8*)(Ash + row_l*200 + c0 + j*8) = *(ushort8*)(vb2 + j*8);
  }
  __syncthreads();
  const int lane = tid & 63, w = tid >> 6;
  const int wm = w & 1, wn = w >> 1;
  const int n = lane & 15, q = lane >> 4;
  const int m0 = blockIdx.x*32 + wm*16;
  f32x4 acc[3] = {};
#pragma unroll
  for (int k32 = 0; k32 < 6; k32++){
    int kb = k32*32 + q*8;
    short8 a = *(const short8*)(Ash + (wm*16 + n)*200 + kb);
#pragma unroll
    for (int j = 0; j < 3; j++){
      int nt = wn*3 + j;
      short8 bfr = *(const short8*)(p.Wfout + ((size_t)(k32*6 + nt)*64 + lane)*8);
      acc[j] = __builtin_amdgcn_mfma_f32_16x16x32_bf16(a, bfr, acc[j], 0, 0, 0);
    }
  }
#pragma unroll
  for (int j = 0; j < 3; j++){
    int nn = wn*48 + j*16 + n;
    float bv = p.bout[nn];
#pragma unroll
    for (int reg = 0; reg < 4; reg++){
      int m = m0 + q*4 + reg;
      p.out[(size_t)m*96 + nn] = acc[j][reg] + bv;
    }
  }
}

extern "C" void kernel_launch(void* const* d_in, const int* in_sizes, int n_in,
                              void* d_out, int out_size, void* d_ws, size_t ws_size,
                              hipStream_t stream)
{
  float* ws = (float*)d_ws;
  Pm p;
  p.x      = (const float*)d_in[0];
  p.Win    = (const float*)d_in[1];
  p.bin    = (const float*)d_in[2];
  p.cw     = (const float*)d_in[3];
  p.cb     = (const float*)d_in[4];
  p.Wxp    = (const float*)d_in[5];
  p.bxp    = (const float*)d_in[6];
  p.Wdt    = (const float*)d_in[7];
  p.bdt    = (const float*)d_in[8];
  p.Alog   = (const float*)d_in[9];
  p.Dskip  = (const float*)d_in[10];
  p.dtb    = (const float*)d_in[11];
  p.Wout   = (const float*)d_in[12];
  p.bout   = (const float*)d_in[13];
  p.gamma  = (const float*)d_in[14];
  p.beta   = (const float*)d_in[15];
  p.out    = (float*)d_out;

  p.xx     = ws;                 // 1572864
  p.zs     = ws + 1572864;       // 1572864
  p.xc     = ws + 3145728;       // 1572864
  p.xdbl   = ws + 4718592;       // 1572864
  p.ysb    = ws + 6291456;       // 6291456
  p.Sb     = ws + 12582912;      // 6291456  [wid][lane][16]
  p.H0loc  = ws + 18874368;      // 6291456  [wid][lane][16]
  p.sdtb   = ws + 25165824;      // 393216
  p.dts_c  = ws + 25559040;      // 196608
  p.ylcs   = ws + 25755648;      // 12582912 paired {y0,cs0,y1,cs1}
  p.cloc   = ws + 38338560;      // 393216
  p.SpanS  = ws + 38731776;      // 196608
  p.SpanC  = ws + 38928384;      // 12288
  p.H0span = ws + 38940672;      // 196608
  p.xcb    = (unsigned short*)(ws + 39137280); // 1572864 ushort
  p.xcTb   = p.xcb + 1572864;                  // 1572864 ushort
  p.Wf     = (unsigned short*)(ws + 40710144); // 147456 ushort
  p.Wfin   = (unsigned short*)(ws + 40783872); // 36864 ushort
  p.Wfout  = (unsigned short*)(ws + 40802304); // 18432 ushort

  k_pack   <<<99,              256, 0, stream>>>(p);
  k_gemm_in<<<256,             256, 0, stream>>>(p);
  k_conv   <<<1536,            256, 0, stream>>>(p);
  k_xdbl   <<<dim3(64, 2, 2),  256, 0, stream>>>(p);
  k_scanA  <<<1536,            256, 0, stream>>>(p);
  k_scanB1 <<<768,             256, 0, stream>>>(p);
  k_scanB2 <<<96,              256, 0, stream>>>(p);
  k_scanC  <<<1536,            256, 0, stream>>>(p);
  k_lngemm <<<256,             256, 0, stream>>>(p);
}

// Round 10
// 207.959 us; speedup vs baseline: 5.4230x; 1.1492x over previous
//
#include <hip/hip_runtime.h>
#include <cstdint>
#include <cstddef>

// SS2D: B=2, H=W=64 (L=4096), D_MODEL=96, D_INNER=192, K=4 dirs, N=16 states, DT_RANK=6.
// R10-R15: plateau 207-210us. R16/R17: cooperative grid.sync ~115us/barrier -> 1127us, dead.
// R18: Pm-struct-by-value REGRESSED +30us (lost __restrict__ no-alias; scanA VGPR 64 -> spills,
//      VALUBusy 36%). Gained counters: scanA is top kernel (~56us degraded / ~45 healthy;
//      26% achievable BW), LDS conflicts 0, pipeline HBM ~280MB.
// R19: restore R15 individual __restrict__ args verbatim (the 208.8us configuration);
//      keep xdbl double-buffered Wf staging (6 barriers not 12 at 1 block/CU).

#define CHUNK 16
#define NCK   256   // 4096 / CHUNK
#define SPAN  32    // chunks per span
#define NSP   8     // NCK / SPAN

#if __has_builtin(__builtin_amdgcn_exp2f)
#define EXP2(x) __builtin_amdgcn_exp2f(x)
#else
#define EXP2(x) exp2f(x)
#endif
#define LOG2E 1.44269504088896340736f
#define LN2   0.69314718055994530942f

typedef __attribute__((ext_vector_type(8))) short short8;
typedef __attribute__((ext_vector_type(8))) unsigned short ushort8;
typedef __attribute__((ext_vector_type(4))) float f32x4;

__device__ __forceinline__ float siluf(float x){ return x * (1.f/(1.f+__expf(-x))); }
__device__ __forceinline__ float softplus_fast(float v){
  float e  = EXP2(v*LOG2E);
  float sp = LN2*__log2f(1.f + e);
  return (v > 20.f) ? v : sp;
}
__device__ __forceinline__ unsigned short f2b(float f){
  uint32_t u = __float_as_uint(f);
  uint32_t r = (u + 0x7fffu + ((u>>16)&1u)) >> 16;
  return (unsigned short)r;
}
__device__ __forceinline__ short8 cast8(const float* p){
  float4 f0 = *(const float4*)p;
  float4 f1 = *(const float4*)(p+4);
  unsigned short t[8] = {f2b(f0.x),f2b(f0.y),f2b(f0.z),f2b(f0.w),
                         f2b(f1.x),f2b(f1.y),f2b(f1.z),f2b(f1.w)};
  return *(short8*)t;
}

// ---------------- Stage 0: pack W_xp + W_in + W_out into fragment-ordered bf16 ----------------
__global__ __launch_bounds__(256) void k_pack(
    const float* __restrict__ Wxp, const float* __restrict__ Win,
    const float* __restrict__ Wout,
    unsigned short* __restrict__ Wf, unsigned short* __restrict__ Wfin,
    unsigned short* __restrict__ Wfout)
{
  int tid = blockIdx.x*256 + threadIdx.x;   // 25344 lane-entries total
  int lane = tid & 63;
  int n = lane & 15, q = lane >> 4;
  if (tid < 18432){
    int rest = tid >> 6;
    int pt = rest % 6; rest /= 6;
    int k32 = rest & 3; rest >>= 2;
    int kc = rest % 6; int ph = rest / 6;
    int p = ph*96 + pt*16 + n;
    int kbase = kc*128 + k32*32 + q*8;
    unsigned short v[8];
#pragma unroll
    for (int j = 0; j < 8; j++)
      v[j] = (p < 152) ? f2b(Wxp[(size_t)p*768 + kbase + j]) : (unsigned short)0;
    *(ushort8*)(Wf + (size_t)tid*8) = *(ushort8*)v;
  } else if (tid < 23040){
    int e = tid - 18432;
    int rest = e >> 6;
    int nt = rest % 24, k32 = rest / 24;
    int p = nt*16 + n;
    int kbase = k32*32 + q*8;
    unsigned short v[8];
#pragma unroll
    for (int j = 0; j < 8; j++) v[j] = f2b(Win[(size_t)p*96 + kbase + j]);
    *(ushort8*)(Wfin + (size_t)e*8) = *(ushort8*)v;
  } else if (tid < 25344){
    int e = tid - 23040;
    int rest = e >> 6;
    int nt = rest % 6, k32 = rest / 6;
    int p = nt*16 + n;
    int kbase = k32*32 + q*8;
    unsigned short v[8];
#pragma unroll
    for (int j = 0; j < 8; j++) v[j] = f2b(Wout[(size_t)p*192 + kbase + j]);
    *(ushort8*)(Wfout + (size_t)e*8) = *(ushort8*)v;
  }
}

// ---------------- Stage 1 (MFMA): xz = x @ W_in^T + b_in; split -> xx, silu(z) ----------------
__global__ __launch_bounds__(256) void k_gemm_in(
    const float* __restrict__ x, const unsigned short* __restrict__ Wfin,
    const float* __restrict__ bias, float* __restrict__ xx, float* __restrict__ zs)
{
  const int tid = threadIdx.x;
  const int lane = tid & 63, w = tid >> 6;
  const int m0 = blockIdx.x*32;
  const int n = lane & 15, q = lane >> 4;
  f32x4 acc[2][6] = {};
#pragma unroll
  for (int k32 = 0; k32 < 3; k32++){
    int kb = k32*32 + q*8;
    short8 a[2];
#pragma unroll
    for (int mf = 0; mf < 2; mf++)
      a[mf] = cast8(x + (size_t)(m0 + mf*16 + n)*96 + kb);
#pragma unroll
    for (int j = 0; j < 6; j++){
      int nt = w*6 + j;
      short8 bfr = *(const short8*)(Wfin + ((size_t)(k32*24 + nt)*64 + lane)*8);
#pragma unroll
      for (int mf = 0; mf < 2; mf++)
        acc[mf][j] = __builtin_amdgcn_mfma_f32_16x16x32_bf16(a[mf], bfr, acc[mf][j], 0, 0, 0);
    }
  }
#pragma unroll
  for (int mf = 0; mf < 2; mf++)
#pragma unroll
    for (int j = 0; j < 6; j++){
      int nn = w*96 + j*16 + n;
      float bv = bias[nn];
#pragma unroll
      for (int reg = 0; reg < 4; reg++){
        int l = m0 + mf*16 + q*4 + reg;
        float v = acc[mf][j][reg] + bv;
        if (nn < 192) xx[(size_t)l*192 + nn] = v;
        else          zs[(size_t)l*192 + (nn-192)] = siluf(v);
      }
    }
}

// ---------------- Stage 2: depthwise 3x3 conv + silu (4 channels/thread, float4) -------------
__global__ __launch_bounds__(256) void k_conv(
    const float* __restrict__ xx, const float* __restrict__ cw, const float* __restrict__ cb,
    float* __restrict__ xc,
    unsigned short* __restrict__ xcb, unsigned short* __restrict__ xcTb)
{
  int gid = blockIdx.x*256 + threadIdx.x;   // 393216 = 2*4096*48
  int c4 = gid % 48; int c = c4*4;
  int l = (gid/48) & 4095;
  int b = gid / (48*4096);
  int h = l >> 6, w = l & 63;
  float sx = 0.f, sy = 0.f, sz = 0.f, sw = 0.f;
#pragma unroll
  for (int kh = 0; kh < 3; kh++){
    int h2 = h + kh - 1;
    if ((unsigned)h2 >= 64u) continue;
#pragma unroll
    for (int kw = 0; kw < 3; kw++){
      int w2 = w + kw - 1;
      if ((unsigned)w2 >= 64u) continue;
      float4 v = *(const float4*)(xx + ((size_t)b*4096 + h2*64 + w2)*192 + c);
      int o = kh*3 + kw;
      sx = fmaf(v.x, cw[(c+0)*9 + o], sx);
      sy = fmaf(v.y, cw[(c+1)*9 + o], sy);
      sz = fmaf(v.z, cw[(c+2)*9 + o], sz);
      sw = fmaf(v.w, cw[(c+3)*9 + o], sw);
    }
  }
  float4 cbv = *(const float4*)(cb + c);
  float4 s;
  s.x = siluf(sx + cbv.x); s.y = siluf(sy + cbv.y);
  s.z = siluf(sz + cbv.z); s.w = siluf(sw + cbv.w);
  unsigned short sb[4] = {f2b(s.x), f2b(s.y), f2b(s.z), f2b(s.w)};
  size_t i0 = ((size_t)b*4096 + l)*192 + c;
  *(float4*)(xc + i0) = s;
  *(uint2*)(xcb + i0) = *(uint2*)sb;
  int tl = (l & 63)*64 + (l >> 6);
  *(uint2*)(xcTb + ((size_t)b*4096 + tl)*192 + c) = *(uint2*)sb;
}

// ---------------- Stage 3 (MFMA): xdbl, double-buffered Wf staging (R18 keep) ----------------
// grid (64,2,2) = 256 blocks (1/CU). LDS 48KB: stage kc+1 under MFMA(kc); 1 barrier/kc.
__global__ __launch_bounds__(256) void k_gemm_xdbl(
    const unsigned short* __restrict__ xcb, const unsigned short* __restrict__ xcTb,
    const unsigned short* __restrict__ Wf, const float* __restrict__ bxp,
    float* __restrict__ xdbl, float* __restrict__ dts_c)
{
  __shared__ unsigned short Bsh[2*12288];   // 48 KB
  const int tid = threadIdx.x;
  const int lane = tid & 63, w = tid >> 6;
  const int wl = w & 1, wp = w >> 1;
  const int l0 = blockIdx.x*64, ph = blockIdx.y, b = blockIdx.z;
  const int n = lane & 15, q = lane >> 4;
  f32x4 acc[2][3] = {};
  const unsigned short* slab0 = Wf + (size_t)ph*6*12288;
  {
    const ushort8* srcp = (const ushort8*)slab0;
#pragma unroll
    for (int t = 0; t < 6; t++) ((ushort8*)Bsh)[tid + t*256] = srcp[tid + t*256];
  }
  __syncthreads();
  int buf = 0;
  for (int kc = 0; kc < 6; kc++){
    if (kc < 5){
      const ushort8* srcp = (const ushort8*)(slab0 + (size_t)(kc+1)*12288);
      ushort8* dst = (ushort8*)(Bsh + (buf^1)*12288);
#pragma unroll
      for (int t = 0; t < 6; t++) dst[tid + t*256] = srcp[tid + t*256];
    }
    const unsigned short* Bcur = Bsh + buf*12288;
#pragma unroll
    for (int k32 = 0; k32 < 4; k32++){
      int kk = kc*128 + k32*32;
      int dir = kk/192; int ch = kk%192 + q*8;
      const unsigned short* sp = (dir & 1) ? xcTb : xcb;
      bool rev = (dir >= 2);
      short8 a[2];
#pragma unroll
      for (int mt = 0; mt < 2; mt++){
        int ls = l0 + wl*32 + mt*16 + n;
        int row = rev ? 4095 - ls : ls;
        a[mt] = *(const short8*)(sp + ((size_t)b*4096 + row)*192 + ch);
      }
#pragma unroll
      for (int j = 0; j < 3; j++){
        short8 bfr = *(const short8*)&Bcur[((size_t)(k32*6 + wp*3 + j)*64 + lane)*8];
#pragma unroll
        for (int mt = 0; mt < 2; mt++)
          acc[mt][j] = __builtin_amdgcn_mfma_f32_16x16x32_bf16(a[mt], bfr, acc[mt][j], 0, 0, 0);
      }
    }
    __syncthreads();
    buf ^= 1;
  }
#pragma unroll
  for (int mt = 0; mt < 2; mt++)
#pragma unroll
    for (int j = 0; j < 3; j++){
      int p = ph*96 + (wp*3+j)*16 + n;
      if (p < 152){
        int k = p/38, pp = p%38;
        int off = (pp < 6) ? pp : pp + 2;
        float bias = bxp[p];
#pragma unroll
        for (int reg = 0; reg < 4; reg++){
          int l = l0 + wl*32 + mt*16 + q*4 + reg;
          float val = acc[mt][j][reg] + bias;
          xdbl[(((size_t)b*4 + k)*4096 + l)*48 + off] = val;
          if (pp < 6) dts_c[((size_t)b*4096 + l)*24 + k*6 + pp] = val;
        }
      }
    }
}

// ---------------- Selective scan A: dt + local recurrence; paired {y,cs} float4 stream --------
__global__ __launch_bounds__(256) void k_scanA(
    const float* __restrict__ xc, const float* __restrict__ xdbl,
    const float* __restrict__ dts_c,
    const float* __restrict__ A_log, const float* __restrict__ Wdt,
    const float* __restrict__ bdt, const float* __restrict__ dtbias,
    const float* __restrict__ Dskip,
    float* __restrict__ ylcs, float* __restrict__ sdtb, float* __restrict__ Sb)
{
  const int lane = threadIdx.x & 63;
  const int wid  = __builtin_amdgcn_readfirstlane(blockIdx.x*4 + (threadIdx.x >> 6));
  const int ck = wid & (NCK-1); const int g = wid / NCK;
  const int dblk = g % 3; const int bk = g / 3;
  const int k = bk & 3; const int b = bk >> 2;
  const int d = dblk*64 + lane; const int ch = k*192 + d;
  float An[16];  // -exp(A_log)*log2e
  {
    const float4* ap = (const float4*)(A_log + (size_t)ch*16);
#pragma unroll
    for (int i = 0; i < 4; i++){
      float4 t = ap[i];
      An[4*i+0] = -LOG2E*__expf(t.x); An[4*i+1] = -LOG2E*__expf(t.y);
      An[4*i+2] = -LOG2E*__expf(t.z); An[4*i+3] = -LOG2E*__expf(t.w);
    }
  }
  float Wr[24];
#pragma unroll
  for (int r = 0; r < 24; r++) Wr[r] = Wdt[(size_t)ch*24 + r];
  const float bsum = bdt[ch] + dtbias[ch];
  const float Dv = Dskip[ch];
  const int l0 = ck*CHUNK;
  const bool rev = (k >= 2);
  const int tr = k & 1;
  const int T0 = tr ? ((l0 & 63)*64 + (l0 >> 6)) : l0;
  const int rs = tr ? 64 : 1;
  const int row0 = rev ? 4095 - T0 : T0;
  const int rstep = (rev ? -rs : rs)*192;
  const float* up  = xc + ((size_t)b*4096 + row0)*192 + d;
  const float* qc  = dts_c + ((size_t)b*4096 + l0)*24;
  const float* xbc = xdbl + (((size_t)b*4 + k)*4096 + l0)*48;
  float* ylp = ylcs + ((((size_t)b*4 + k)*2048 + (size_t)ck*(CHUNK/2))*192 + d)*4;
  float h[16];
#pragma unroll
  for (int n = 0; n < 16; n++) h[n] = 0.f;
  float sdt = 0.f;
#pragma unroll 4
  for (int tp = 0; tp < CHUNK/2; tp++){
    float y2[2], cs2[2];
#pragma unroll
    for (int e = 0; e < 2; e++){
      float u  = up[0];
      float4 B0 = *(const float4*)(xbc + 8);
      float4 B1 = *(const float4*)(xbc + 12);
      float4 B2 = *(const float4*)(xbc + 16);
      float4 B3 = *(const float4*)(xbc + 20);
      float4 C0 = *(const float4*)(xbc + 24);
      float4 C1 = *(const float4*)(xbc + 28);
      float4 C2 = *(const float4*)(xbc + 32);
      float4 C3 = *(const float4*)(xbc + 36);
      float Bv[16] = {B0.x,B0.y,B0.z,B0.w, B1.x,B1.y,B1.z,B1.w,
                      B2.x,B2.y,B2.z,B2.w, B3.x,B3.y,B3.z,B3.w};
      float Cv[16] = {C0.x,C0.y,C0.z,C0.w, C1.x,C1.y,C1.z,C1.w,
                      C2.x,C2.y,C2.z,C2.w, C3.x,C3.y,C3.z,C3.w};
      float4 q0 = *(const float4*)(qc);
      float4 q1 = *(const float4*)(qc + 4);
      float4 q2 = *(const float4*)(qc + 8);
      float4 q3 = *(const float4*)(qc + 12);
      float4 q4 = *(const float4*)(qc + 16);
      float4 q5 = *(const float4*)(qc + 20);
      float qv[24] = {q0.x,q0.y,q0.z,q0.w, q1.x,q1.y,q1.z,q1.w,
                      q2.x,q2.y,q2.z,q2.w, q3.x,q3.y,q3.z,q3.w,
                      q4.x,q4.y,q4.z,q4.w, q5.x,q5.y,q5.z,q5.w};
      float v0 = bsum, v1 = 0.f, v2 = 0.f, v3 = 0.f;
#pragma unroll
      for (int r = 0; r < 24; r += 4){
        v0 = fmaf(Wr[r+0], qv[r+0], v0);
        v1 = fmaf(Wr[r+1], qv[r+1], v1);
        v2 = fmaf(Wr[r+2], qv[r+2], v2);
        v3 = fmaf(Wr[r+3], qv[r+3], v3);
      }
      float dt = softplus_fast((v0+v1) + (v2+v3));
      float dtu = dt*u;
      sdt += dt;
      float y0 = u*Dv;
      float y1 = 0.f;
#pragma unroll
      for (int n = 0; n < 16; n += 2){
        float dA0 = EXP2(dt*An[n]);
        float dA1 = EXP2(dt*An[n+1]);
        h[n]   = fmaf(dA0, h[n],   dtu*Bv[n]);
        h[n+1] = fmaf(dA1, h[n+1], dtu*Bv[n+1]);
        y0 = fmaf(h[n],   Cv[n],   y0);
        y1 = fmaf(h[n+1], Cv[n+1], y1);
      }
      y2[e] = y0 + y1; cs2[e] = sdt;
      qc += 24; xbc += 48; up += rstep;
    }
    *(float4*)ylp = make_float4(y2[0], cs2[0], y2[1], cs2[1]);
    ylp += 768;
  }
  size_t rb = ((size_t)wid*64 + lane);
  sdtb[rb] = sdt;
  *(float4*)(Sb + rb*16 + 0)  = make_float4(h[0], h[1], h[2], h[3]);
  *(float4*)(Sb + rb*16 + 4)  = make_float4(h[4], h[5], h[6], h[7]);
  *(float4*)(Sb + rb*16 + 8)  = make_float4(h[8], h[9], h[10],h[11]);
  *(float4*)(Sb + rb*16 + 12) = make_float4(h[12],h[13],h[14],h[15]);
}

// ---------------- scanB1: intra-span (32-chunk) exclusive prefixes, n-fastest thread map ------
__global__ __launch_bounds__(256) void k_scanB1(
    const float* __restrict__ A_log, const float* __restrict__ sdtb,
    const float* __restrict__ Sb,
    float* __restrict__ H0loc, float* __restrict__ cloc,
    float* __restrict__ SpanS, float* __restrict__ SpanC)
{
  int tid = blockIdx.x*256 + threadIdx.x;   // 196608
  int n = tid & 15; int lane = (tid >> 4) & 63;
  int span = (tid >> 10) & (NSP-1); int g = tid >> 13;
  int dblk = g % 3; int bk = g / 3; int k = bk & 3;
  int ch = k*192 + dblk*64 + lane;
  float An = -LOG2E*__expf(A_log[(size_t)ch*16 + n]);
  float h = 0.f, cs = 0.f;
  int wid0 = g*NCK + span*SPAN;
#pragma unroll 8
  for (int c = 0; c < SPAN; c++){
    size_t rb = ((size_t)(wid0 + c)*64 + lane);
    H0loc[rb*16 + n] = h;
    if (n == 0) cloc[rb] = cs;
    float sd = sdtb[rb];
    h = fmaf(EXP2(An*sd), h, Sb[rb*16 + n]);
    cs += sd;
  }
  size_t sp = ((size_t)(g*NSP + span)*64 + lane);
  SpanS[sp*16 + n] = h;
  if (n == 0) SpanC[sp] = cs;
}

// ---------------- scanB2: scan the 8-span chains (tiny), n-fastest map ------------------------
__global__ __launch_bounds__(64) void k_scanB2(
    const float* __restrict__ A_log, const float* __restrict__ SpanS,
    const float* __restrict__ SpanC, float* __restrict__ H0span)
{
  int tid = blockIdx.x*64 + threadIdx.x;  // 24576
  int n = tid & 15; int lane = (tid >> 4) & 63; int g = tid >> 10;
  int dblk = g % 3; int bk = g / 3; int k = bk & 3;
  int ch = k*192 + dblk*64 + lane;
  float An = -LOG2E*__expf(A_log[(size_t)ch*16 + n]);
  float h = 0.f;
#pragma unroll
  for (int span = 0; span < NSP; span++){
    size_t sp = ((size_t)(g*NSP + span)*64 + lane);
    H0span[sp*16 + n] = h;
    h = fmaf(EXP2(An*SpanC[sp]), h, SpanS[sp*16 + n]);
  }
}

// ---------------- Selective scan C: y = C.(exp2(An*csdt) o H0) + yloc; float4 everywhere ------
__global__ __launch_bounds__(256) void k_scanC(
    const float* __restrict__ xdbl, const float* __restrict__ A_log,
    const float* __restrict__ ylcs,
    const float* __restrict__ H0loc, const float* __restrict__ cloc,
    const float* __restrict__ H0span,
    float* __restrict__ ys)
{
  const int lane = threadIdx.x & 63;
  const int wid  = __builtin_amdgcn_readfirstlane(blockIdx.x*4 + (threadIdx.x >> 6));
  const int ck = wid & (NCK-1); const int g = wid / NCK;
  const int dblk = g % 3; const int bk = g / 3;
  const int k = bk & 3; const int b = bk >> 2;
  const int d = dblk*64 + lane; const int ch = k*192 + d;
  float An[16];  // -exp(A_log)*log2e
  {
    const float4* ap = (const float4*)(A_log + (size_t)ch*16);
#pragma unroll
    for (int i = 0; i < 4; i++){
      float4 t = ap[i];
      An[4*i+0] = -LOG2E*__expf(t.x); An[4*i+1] = -LOG2E*__expf(t.y);
      An[4*i+2] = -LOG2E*__expf(t.z); An[4*i+3] = -LOG2E*__expf(t.w);
    }
  }
  const int l0 = ck*CHUNK;
  const bool rev = (k >= 2);
  const int tr = k & 1;
  const int T0 = tr ? ((l0 & 63)*64 + (l0 >> 6)) : l0;
  const int rs = tr ? 64 : 1;
  const int row0 = rev ? 4095 - T0 : T0;
  const int rstep = (rev ? -rs : rs)*192;
  const float* xbc = xdbl + (((size_t)b*4 + k)*4096 + l0)*48;
  const float* ylp = ylcs + ((((size_t)b*4 + k)*2048 + (size_t)ck*(CHUNK/2))*192 + d)*4;
  float* ysp = ys + ((size_t)(k*2 + b))*4096*192 + (size_t)row0*192 + d;
  // H0 = H0loc + exp2(An*cloc)*H0span (float4 combine, once per wave)
  float h0r[16];
  {
    size_t rb = ((size_t)wid*64 + lane);
    float cl = cloc[rb];
    size_t sp = ((size_t)(g*NSP + (ck >> 5))*64 + lane);
#pragma unroll
    for (int i = 0; i < 4; i++){
      float4 hl = *(const float4*)(H0loc + rb*16 + i*4);
      float4 hs = *(const float4*)(H0span + sp*16 + i*4);
      h0r[4*i+0] = fmaf(EXP2(An[4*i+0]*cl), hs.x, hl.x);
      h0r[4*i+1] = fmaf(EXP2(An[4*i+1]*cl), hs.y, hl.y);
      h0r[4*i+2] = fmaf(EXP2(An[4*i+2]*cl), hs.z, hl.z);
      h0r[4*i+3] = fmaf(EXP2(An[4*i+3]*cl), hs.w, hl.w);
    }
  }
#pragma unroll 4
  for (int tp = 0; tp < CHUNK/2; tp++){
    float4 yc = *(const float4*)ylp;
#pragma unroll
    for (int e = 0; e < 2; e++){
      float yl = e ? yc.z : yc.x;
      float cs = e ? yc.w : yc.y;
      float4 C0 = *(const float4*)(xbc + 24);
      float4 C1 = *(const float4*)(xbc + 28);
      float4 C2 = *(const float4*)(xbc + 32);
      float4 C3 = *(const float4*)(xbc + 36);
      float Cv[16] = {C0.x,C0.y,C0.z,C0.w, C1.x,C1.y,C1.z,C1.w,
                      C2.x,C2.y,C2.z,C2.w, C3.x,C3.y,C3.z,C3.w};
      float y0 = yl, y1 = 0.f;
#pragma unroll
      for (int n = 0; n < 16; n += 2){
        float e0 = EXP2(An[n]*cs)   * h0r[n];
        float e1 = EXP2(An[n+1]*cs) * h0r[n+1];
        y0 = fmaf(Cv[n],   e0, y0);
        y1 = fmaf(Cv[n+1], e1, y1);
      }
      ysp[0] = y0 + y1;
      xbc += 48; ysp += rstep;
    }
    ylp += 768;
  }
}

// ---------------- Stage 6+7 fused: merge + LayerNorm*silu(z) -> LDS bf16 -> MFMA out ----------
__global__ __launch_bounds__(256) void k_lngemm(
    const float* __restrict__ ys, const float* __restrict__ zs,
    const float* __restrict__ gamma, const float* __restrict__ beta,
    const unsigned short* __restrict__ Wfout, const float* __restrict__ bout,
    float* __restrict__ out)
{
  __shared__ unsigned short Ash[32*200];   // 12.5 KB, stride 200 ushorts
  const int tid = threadIdx.x;
  {
    const int row_l = tid >> 3, o = tid & 7;
    const int row = blockIdx.x*32 + row_l;
    const int b = row >> 12, l = row & 4095;
    const int c0 = o*24;
    float s[24];
#pragma unroll
    for (int j = 0; j < 6; j++){
      float sx = 0.f, sy = 0.f, sz = 0.f, sw = 0.f;
#pragma unroll
      for (int k = 0; k < 4; k++){
        float4 t = *(const float4*)(ys + (((size_t)(k*2+b))*4096 + l)*192 + c0 + j*4);
        sx += t.x; sy += t.y; sz += t.z; sw += t.w;
      }
      s[j*4+0]=sx; s[j*4+1]=sy; s[j*4+2]=sz; s[j*4+3]=sw;
    }
    float tot = 0.f;
#pragma unroll
    for (int j = 0; j < 24; j++) tot += s[j];
#pragma unroll
    for (int off = 1; off < 8; off <<= 1) tot += __shfl_xor(tot, off);
    float mean = tot*(1.f/192.f);
    float vs = 0.f;
#pragma unroll
    for (int j = 0; j < 24; j++){ s[j] -= mean; vs = fmaf(s[j], s[j], vs); }
#pragma unroll
    for (int off = 1; off < 8; off <<= 1) vs += __shfl_xor(vs, off);
    float rstd = rsqrtf(vs*(1.f/192.f) + 1e-5f);
    unsigned short vb[24];
#pragma unroll
    for (int j = 0; j < 6; j++){
      float4 g4 = *(const float4*)(gamma + c0 + j*4);
      float4 b4 = *(const float4*)(beta  + c0 + j*4);
      float4 z4 = *(const float4*)(zs + (size_t)row*192 + c0 + j*4);
      vb[j*4+0] = f2b((s[j*4+0]*rstd*g4.x + b4.x)*z4.x);
      vb[j*4+1] = f2b((s[j*4+1]*rstd*g4.y + b4.y)*z4.y);
      vb[j*4+2] = f2b((s[j*4+2]*rstd*g4.z + b4.z)*z4.z);
      vb[j*4+3] = f2b((s[j*4+3]*rstd*g4.w + b4.w)*z4.w);
    }
#pragma unroll
    for (int j = 0; j < 3; j++)
      *(ushort8*)(Ash + row_l*200 + c0 + j*8) = *(ushort8*)(vb + j*8);
  }
  __syncthreads();
  const int lane = tid & 63, w = tid >> 6;
  const int wm = w & 1, wn = w >> 1;
  const int n = lane & 15, q = lane >> 4;
  const int m0 = blockIdx.x*32 + wm*16;
  f32x4 acc[3] = {};
#pragma unroll
  for (int k32 = 0; k32 < 6; k32++){
    int kb = k32*32 + q*8;
    short8 a = *(const short8*)(Ash + (wm*16 + n)*200 + kb);
#pragma unroll
    for (int j = 0; j < 3; j++){
      int nt = wn*3 + j;
      short8 bfr = *(const short8*)(Wfout + ((size_t)(k32*6 + nt)*64 + lane)*8);
      acc[j] = __builtin_amdgcn_mfma_f32_16x16x32_bf16(a, bfr, acc[j], 0, 0, 0);
    }
  }
#pragma unroll
  for (int j = 0; j < 3; j++){
    int nn = wn*48 + j*16 + n;
    float bv = bout[nn];
#pragma unroll
    for (int reg = 0; reg < 4; reg++){
      int m = m0 + q*4 + reg;
      out[(size_t)m*96 + nn] = acc[j][reg] + bv;
    }
  }
}

extern "C" void kernel_launch(void* const* d_in, const int* in_sizes, int n_in,
                              void* d_out, int out_size, void* d_ws, size_t ws_size,
                              hipStream_t stream)
{
  const float* x      = (const float*)d_in[0];
  const float* W_in   = (const float*)d_in[1];
  const float* b_in   = (const float*)d_in[2];
  const float* conv_w = (const float*)d_in[3];
  const float* conv_b = (const float*)d_in[4];
  const float* W_xp   = (const float*)d_in[5];
  const float* b_xp   = (const float*)d_in[6];
  const float* W_dt   = (const float*)d_in[7];
  const float* b_dt   = (const float*)d_in[8];
  const float* A_log  = (const float*)d_in[9];
  const float* D_skip = (const float*)d_in[10];
  const float* dt_bias= (const float*)d_in[11];
  const float* W_out  = (const float*)d_in[12];
  const float* b_out  = (const float*)d_in[13];
  const float* gamma  = (const float*)d_in[14];
  const float* beta   = (const float*)d_in[15];
  float* out = (float*)d_out;

  float* ws     = (float*)d_ws;
  float* xx     = ws;                 // 1572864
  float* zs     = ws + 1572864;       // 1572864
  float* xc     = ws + 3145728;       // 1572864
  float* xdbl   = ws + 4718592;       // 1572864
  float* ysb    = ws + 6291456;       // 6291456
  float* Sb     = ws + 12582912;      // 6291456  [wid][lane][16]
  float* H0loc  = ws + 18874368;      // 6291456  [wid][lane][16]
  float* sdtb   = ws + 25165824;      // 393216   [wid][lane]
  float* dts_c  = ws + 25559040;      // 196608
  float* ylcs   = ws + 25755648;      // 12582912 paired {y0,cs0,y1,cs1}
  float* cloc   = ws + 38338560;      // 393216   [wid][lane]
  float* SpanS  = ws + 38731776;      // 196608   [sp][lane][16]
  float* SpanC  = ws + 38928384;      // 12288    [sp][lane]
  float* H0span = ws + 38940672;      // 196608   [sp][lane][16]
  unsigned short* xcb   = (unsigned short*)(ws + 39137280); // 1572864 ushort
  unsigned short* xcTb  = xcb + 1572864;                    // 1572864 ushort
  unsigned short* Wf    = (unsigned short*)(ws + 40710144); // 147456 ushort
  unsigned short* Wfin  = (unsigned short*)(ws + 40783872); // 36864 ushort
  unsigned short* Wfout = (unsigned short*)(ws + 40802304); // 18432 ushort

  k_pack     <<<99,             256, 0, stream>>>(W_xp, W_in, W_out, Wf, Wfin, Wfout);
  k_gemm_in  <<<256,            256, 0, stream>>>(x, Wfin, b_in, xx, zs);
  k_conv     <<<1536,           256, 0, stream>>>(xx, conv_w, conv_b, xc, xcb, xcTb);
  k_gemm_xdbl<<<dim3(64, 2, 2), 256, 0, stream>>>(xcb, xcTb, Wf, b_xp, xdbl, dts_c);
  k_scanA    <<<1536,           256, 0, stream>>>(xc, xdbl, dts_c, A_log, W_dt, b_dt, dt_bias, D_skip, ylcs, sdtb, Sb);
  k_scanB1   <<<768,            256, 0, stream>>>(A_log, sdtb, Sb, H0loc, cloc, SpanS, SpanC);
  k_scanB2   <<<384,            64,  0, stream>>>(A_log, SpanS, SpanC, H0span);
  k_scanC    <<<1536,           256, 0, stream>>>(xdbl, A_log, ylcs, H0loc, cloc, H0span, ysb);
  k_lngemm   <<<256,            256, 0, stream>>>(ysb, zs, gamma, beta, Wfout, b_out, out);
}